// Round 6
// baseline (162.672 us; speedup 1.0000x reference)
//
#include <hip/hip_runtime.h>
#include <math.h>

#define DM    1024
#define DQK   128
#define BATCH 4
#define SEQ   4096
// 1/sqrt(128) * log2(e) folded into Wq/bq at wcvt time -> softmax uses exp2 directly
#define QSCALE (0.08838834764831845f * 1.4426950408889634f)
#define DEFER_THR 6.0f

typedef _Float16 f16;
typedef _Float16 f16x4 __attribute__((ext_vector_type(4)));
typedef _Float16 f16x8 __attribute__((ext_vector_type(8)));
typedef float    f32x4 __attribute__((ext_vector_type(4)));

// ---------------- W convert/transpose pre-kernel ----------------
__global__ __launch_bounds__(256) void wcvt_kernel(
    const float* __restrict__ Wq, const float* __restrict__ bq,
    const float* __restrict__ Wk, const float* __restrict__ bk,
    const float* __restrict__ Wv, const float* __restrict__ bv,
    f16* __restrict__ wt, float* __restrict__ biasf)
{
    const int sel = blockIdx.x >> 3;
    const int k0  = (blockIdx.x & 7) * 128;
    const float* W; const float* b; float sc;
    if (sel == 0)      { W = Wq; b = bq; sc = QSCALE; }
    else if (sel == 1) { W = Wk; b = bk; sc = 1.0f; }
    else               { W = Wv; b = bv; sc = 1.0f; }

    __shared__ f16 tile[128][136];

    #pragma unroll
    for (int it = 0; it < 16; ++it) {
        int flat = threadIdx.x + it * 256;
        int kk   = flat >> 5;
        int c4   = flat & 31;
        float4 w4 = *(const float4*)(W + (size_t)(k0 + kk) * DQK + c4 * 4);
        tile[kk][c4 * 4 + 0] = (f16)(w4.x * sc);
        tile[kk][c4 * 4 + 1] = (f16)(w4.y * sc);
        tile[kk][c4 * 4 + 2] = (f16)(w4.z * sc);
        tile[kk][c4 * 4 + 3] = (f16)(w4.w * sc);
    }
    __syncthreads();

    #pragma unroll
    for (int it = 0; it < 8; ++it) {
        int flat = threadIdx.x + it * 256;
        int n    = flat >> 4;
        int kc   = flat & 15;
        f16x8 v;
        #pragma unroll
        for (int i = 0; i < 8; ++i) v[i] = tile[kc * 8 + i][n];
        *(f16x8*)(wt + (size_t)(sel * 128 + n) * DM + k0 + kc * 8) = v;
    }
    if ((blockIdx.x & 7) == 0 && threadIdx.x < 128)
        biasf[sel * 128 + threadIdx.x] = b[threadIdx.x] * sc;
}

// ---------------- Fused QKV projection, f16 MFMA (unchanged) ----------------
__global__ __launch_bounds__(512, 2) void proj_kernel(
    const float* __restrict__ x, const f16* __restrict__ wt,
    const float* __restrict__ biasf,
    f16* __restrict__ qo, f16* __restrict__ ko, f16* __restrict__ vto)
{
    __shared__ __align__(16) unsigned char smem[50176];

    const int tid  = threadIdx.x;
    const int lane = tid & 63;
    const int w    = tid >> 6;
    const int c    = lane & 15;
    const int g    = lane >> 4;
    const int r0   = blockIdx.x * 64;

    const int srow = tid >> 3;
    const int skq  = tid & 7;
    const float* const xsrc  = x + (size_t)(r0 + srow) * DM + skq * 8;
    const unsigned     swoff = (unsigned)(srow * 128 + ((skq ^ (srow & 7)) * 16));

    f32x4 acc[4][3];
    #pragma unroll
    for (int rf = 0; rf < 4; ++rf)
        #pragma unroll
        for (int nf = 0; nf < 3; ++nf) acc[rf][nf] = (f32x4)0.f;

    float4 xa, xb2;
    auto gload = [&](int t) {
        const float* p = xsrc + t * 64;
        xa  = *(const float4*)p;
        xb2 = *(const float4*)(p + 4);
    };
    auto swrite = [&](int buf) {
        f16x8 h;
        h[0] = (f16)xa.x;  h[1] = (f16)xa.y;  h[2] = (f16)xa.z;  h[3] = (f16)xa.w;
        h[4] = (f16)xb2.x; h[5] = (f16)xb2.y; h[6] = (f16)xb2.z; h[7] = (f16)xb2.w;
        *(f16x8*)(smem + (unsigned)buf * 8192u + swoff) = h;
    };

    gload(0); swrite(0);
    gload(1);
    __syncthreads();

    for (int t = 0; t < 16; ++t) {
        const int cur = t & 1;
        if (t < 15) swrite(cur ^ 1);
        if (t < 14) gload(t + 2);

        f16x8 af[4][2];
        #pragma unroll
        for (int rf = 0; rf < 4; ++rf)
            #pragma unroll
            for (int ks = 0; ks < 2; ++ks)
                af[rf][ks] = *(const f16x8*)(smem + (unsigned)cur * 8192u
                    + (unsigned)((rf * 16 + c) * 128)
                    + (unsigned)((((4 * ks + g) ^ (c & 7)) * 16)));

        #pragma unroll
        for (int nf = 0; nf < 3; ++nf) {
            #pragma unroll
            for (int ks = 0; ks < 2; ++ks) {
                f16x8 bf = *(const f16x8*)(wt
                    + (size_t)(w * 48 + nf * 16 + c) * DM + t * 64 + ks * 32 + g * 8);
                #pragma unroll
                for (int rf = 0; rf < 4; ++rf)
                    acc[rf][nf] = __builtin_amdgcn_mfma_f32_16x16x32_f16(
                        af[rf][ks], bf, acc[rf][nf], 0, 0, 0);
            }
        }
        __syncthreads();
    }

    f16* const tile = (f16*)smem;
    #pragma unroll
    for (int rf = 0; rf < 4; ++rf)
        #pragma unroll
        for (int nf = 0; nf < 3; ++nf) {
            const int n  = w * 48 + nf * 16 + c;
            const float bb = biasf[n];
            #pragma unroll
            for (int r = 0; r < 4; ++r) {
                const int row = rf * 16 + 4 * g + r;
                tile[row * 392 + n] = (f16)(acc[rf][nf][r] + bb);
            }
        }
    __syncthreads();

    #pragma unroll
    for (int it = 0; it < 2; ++it) {
        const int u   = tid + it * 512;
        const int row = u >> 4;
        const int c8  = (u & 15) * 8;
        *(f16x8*)(qo + (size_t)(r0 + row) * DQK + c8) = *(const f16x8*)&tile[row * 392 + c8];
        *(f16x8*)(ko + (size_t)(r0 + row) * DQK + c8) = *(const f16x8*)&tile[row * 392 + 128 + c8];
    }
    const int gb = r0 >> 12;
    const int s0 = r0 & (SEQ - 1);
    #pragma unroll
    for (int it = 0; it < 2; ++it) {
        const int u  = tid + it * 512;
        const int d  = u >> 3;
        const int s8 = (u & 7) * 8;
        f16x8 vv;
        #pragma unroll
        for (int i = 0; i < 8; ++i) vv[i] = tile[(s8 + i) * 392 + 256 + d];
        *(f16x8*)(vto + ((size_t)gb * DQK + d) * SEQ + s0 + s8) = vv;
    }
}

// ---------------- Flash attention: barrier-free, K/V direct from L2 ----------------
// grid 256 x 512 thr (8 waves = (wq 0..1) x (wk 0..3)). No LDS staging: kf/vf frags are
// 16B/lane contiguous global loads (K row-major over d; V^T row-major over s), L2-resident
// (2 MB K+V per batch, batch pinned to an XCD pair). K prefetched 1 tile ahead into a
// second register set; V issued at iter top, consumed after softmax. P exchanged between
// lanes via cvt_pkrtz + ds_bpermute (no storage). LDS only for the final 4-way kv merge.

#define ATTN_STEP(KC, KN, T)                                                              \
    {                                                                                     \
        const int tt = (T);                                                               \
        f16x8 vr[8];                                                                      \
        _Pragma("unroll")                                                                 \
        for (int df = 0; df < 8; ++df)                                                    \
            vr[df] = *(const f16x8*)(vlane + (size_t)tt * 256 + (size_t)df * 131072);     \
        if (tt + 1 < 32) {                                                                \
            _Pragma("unroll")                                                             \
            for (int i = 0; i < 8; ++i)                                                   \
                KN[i] = *(const f16x8*)(klane + (size_t)(tt + 1) * 32768                  \
                            + (size_t)(i >> 2) * 4096 + (size_t)(i & 3) * 64);            \
        }                                                                                 \
        f32x4 s[2][2];                                                                    \
        s[0][0] = (f32x4)0.f; s[0][1] = (f32x4)0.f;                                       \
        s[1][0] = (f32x4)0.f; s[1][1] = (f32x4)0.f;                                       \
        __builtin_amdgcn_s_setprio(1);                                                    \
        _Pragma("unroll")                                                                 \
        for (int ks = 0; ks < 4; ++ks) {                                                  \
            _Pragma("unroll")                                                             \
            for (int m = 0; m < 2; ++m) {                                                 \
                s[m][0] = __builtin_amdgcn_mfma_f32_16x16x32_f16(                         \
                    KC[m * 4 + ks], qf[0][ks], s[m][0], 0, 0, 0);                         \
                s[m][1] = __builtin_amdgcn_mfma_f32_16x16x32_f16(                         \
                    KC[m * 4 + ks], qf[1][ks], s[m][1], 0, 0, 0);                         \
            }                                                                             \
        }                                                                                 \
        __builtin_amdgcn_s_setprio(0);                                                    \
        float mt[2];                                                                      \
        _Pragma("unroll")                                                                 \
        for (int n = 0; n < 2; ++n) {                                                     \
            float a0 = fmaxf(fmaxf(s[0][n][0], s[0][n][1]), fmaxf(s[0][n][2], s[0][n][3]));\
            float a1 = fmaxf(fmaxf(s[1][n][0], s[1][n][1]), fmaxf(s[1][n][2], s[1][n][3]));\
            float v  = fmaxf(a0, a1);                                                     \
            v = fmaxf(v, __shfl_xor(v, 16, 64));                                          \
            v = fmaxf(v, __shfl_xor(v, 32, 64));                                          \
            mt[n] = v;                                                                    \
        }                                                                                 \
        bool need = (mt[0] > m_run[0] + DEFER_THR) || (mt[1] > m_run[1] + DEFER_THR);     \
        if (__any(need)) {                                                                \
            float al[2];                                                                  \
            _Pragma("unroll")                                                             \
            for (int n = 0; n < 2; ++n) {                                                 \
                float mn = fmaxf(m_run[n], mt[n]);                                        \
                al[n] = __builtin_amdgcn_exp2f(m_run[n] - mn);                            \
                m_run[n] = mn;                                                            \
                l_run[n] *= al[n];                                                        \
            }                                                                             \
            float alo[2][4];                                                              \
            _Pragma("unroll")                                                             \
            for (int n = 0; n < 2; ++n)                                                   \
                _Pragma("unroll")                                                         \
                for (int r = 0; r < 4; ++r)                                               \
                    alo[n][r] = __shfl(al[n], 4 * g + r, 16);                             \
            _Pragma("unroll")                                                             \
            for (int n = 0; n < 2; ++n)                                                   \
                _Pragma("unroll")                                                         \
                for (int f = 0; f < 8; ++f)                                               \
                    _Pragma("unroll")                                                     \
                    for (int r = 0; r < 4; ++r) o[n][f][r] *= alo[n][r];                  \
        }                                                                                 \
        _Pragma("unroll")                                                                 \
        for (int m = 0; m < 2; ++m)                                                       \
            _Pragma("unroll")                                                             \
            for (int n = 0; n < 2; ++n)                                                   \
                _Pragma("unroll")                                                         \
                for (int r = 0; r < 4; ++r)                                               \
                    s[m][n][r] = __builtin_amdgcn_exp2f(s[m][n][r] - m_run[n]);           \
        _Pragma("unroll")                                                                 \
        for (int n = 0; n < 2; ++n) {                                                     \
            float ls = ((s[0][n][0] + s[0][n][1]) + (s[0][n][2] + s[0][n][3]))            \
                     + ((s[1][n][0] + s[1][n][1]) + (s[1][n][2] + s[1][n][3]));           \
            ls += __shfl_xor(ls, 16, 64);                                                 \
            ls += __shfl_xor(ls, 32, 64);                                                 \
            l_run[n] += ls;                                                               \
        }                                                                                 \
        int u[2][2][2];                                                                   \
        _Pragma("unroll")                                                                 \
        for (int n = 0; n < 2; ++n)                                                       \
            _Pragma("unroll")                                                             \
            for (int m = 0; m < 2; ++m)                                                   \
                _Pragma("unroll")                                                         \
                for (int p = 0; p < 2; ++p) {                                             \
                    auto h2 = __builtin_amdgcn_cvt_pkrtz(s[m][n][2 * p], s[m][n][2 * p + 1]);\
                    u[n][m][p] = __builtin_bit_cast(int, h2);                             \
                }                                                                         \
        f16x8 pa[2];                                                                      \
        _Pragma("unroll")                                                                 \
        for (int n = 0; n < 2; ++n) {                                                     \
            int paw[4];                                                                   \
            _Pragma("unroll")                                                             \
            for (int j = 0; j < 4; ++j) {                                                 \
                const int addr = (j >> 1) ? addr_h1 : addr_h0;                            \
                int tA = __builtin_amdgcn_ds_bpermute(addr, u[n][0][j & 1]);              \
                int tB = __builtin_amdgcn_ds_bpermute(addr, u[n][1][j & 1]);              \
                paw[j] = hi_m ? tB : tA;                                                  \
            }                                                                             \
            int4 pw = make_int4(paw[0], paw[1], paw[2], paw[3]);                          \
            pa[n] = __builtin_bit_cast(f16x8, pw);                                        \
        }                                                                                 \
        __builtin_amdgcn_s_setprio(1);                                                    \
        _Pragma("unroll")                                                                 \
        for (int df = 0; df < 8; ++df) {                                                  \
            o[0][df] = __builtin_amdgcn_mfma_f32_16x16x32_f16(pa[0], vr[df], o[0][df], 0, 0, 0);\
            o[1][df] = __builtin_amdgcn_mfma_f32_16x16x32_f16(pa[1], vr[df], o[1][df], 0, 0, 0);\
        }                                                                                 \
        __builtin_amdgcn_s_setprio(0);                                                    \
    }

__global__ __launch_bounds__(512, 2) void attn_kernel(
    const f16* __restrict__ qg, const f16* __restrict__ kg,
    const f16* __restrict__ vtg, float* __restrict__ out)
{
    __shared__ float olds[192 * 132];   // [wq][wk-1][32 q][132] merge buffer
    __shared__ float mld[256], lld[256];

    const int tid  = threadIdx.x;
    const int lane = tid & 63;
    const int w    = tid >> 6;      // 0..7
    const int wq   = w >> 2;        // 0..1
    const int wk   = w & 3;         // 0..3
    const int c    = lane & 15;
    const int g    = lane >> 4;     // 0..3

    const int bid = blockIdx.x;
    const int xcd = bid & 7;
    const int bb  = xcd >> 1;
    const int qt  = (bid >> 3) | ((xcd & 1) << 5);
    const int q0  = qt * 64;

    const f16*  qb = qg  + (size_t)bb * SEQ * DQK;
    const char* kB = (const char*)(kg  + (size_t)bb * SEQ * DQK);
    const char* vB = (const char*)(vtg + (size_t)bb * DQK * SEQ);

    // per-lane base addresses for direct K/V fragment loads
    const char* const klane = kB + (size_t)(wk * 32 + c) * 256 + g * 16;
    const char* const vlane = vB + (size_t)c * 8192 + (wk * 32 + g * 8) * 2;

    // Q frags (B-operand for swapped QK^T): q = 16n + c, k(d) = ks*32 + 8g + i
    f16x8 qf[2][4];
    {
        const f16* qr = qb + (size_t)(q0 + wq * 32) * DQK;
        #pragma unroll
        for (int n = 0; n < 2; ++n)
            #pragma unroll
            for (int ks = 0; ks < 4; ++ks)
                qf[n][ks] = *(const f16x8*)(qr + (n * 16 + c) * DQK + ks * 32 + 8 * g);
    }

    f32x4 o[2][8];
    #pragma unroll
    for (int n = 0; n < 2; ++n)
        #pragma unroll
        for (int f = 0; f < 8; ++f) o[n][f] = (f32x4)0.f;
    float m_run[2] = {-3e38f, -3e38f};
    float l_run[2] = {0.f, 0.f};

    // bpermute source-lane byte-addresses (loop-invariant)
    const int addr_h0 = (16 * (2 * (g & 1) + 0) + c) * 4;
    const int addr_h1 = (16 * (2 * (g & 1) + 1) + c) * 4;
    const bool hi_m = (g >= 2);

    // K prologue: tile 0 into kA
    f16x8 kA[8], kBf[8];
    #pragma unroll
    for (int i = 0; i < 8; ++i)
        kA[i] = *(const f16x8*)(klane + (size_t)(i >> 2) * 4096 + (size_t)(i & 3) * 64);

    for (int t = 0; t < 32; t += 2) {
        ATTN_STEP(kA,  kBf, t);
        ATTN_STEP(kBf, kA,  t + 1);
    }

    // ship m, l to O row domain (q = 16n + 4g + r)
    float m_o[2][4], l_o[2][4];
    #pragma unroll
    for (int n = 0; n < 2; ++n)
        #pragma unroll
        for (int r = 0; r < 4; ++r) {
            m_o[n][r] = __shfl(m_run[n], 4 * g + r, 16);
            l_o[n][r] = __shfl(l_run[n], 4 * g + r, 16);
        }

    // ---- merge the 4 kv-splits (per wq) via LDS ----
    if (wk > 0) {
        const int base = (wq * 3 + (wk - 1)) * 32;
        #pragma unroll
        for (int n = 0; n < 2; ++n)
            #pragma unroll
            for (int f = 0; f < 8; ++f)
                #pragma unroll
                for (int r = 0; r < 4; ++r)
                    olds[(size_t)(base + n * 16 + 4 * g + r) * 132 + f * 16 + c] = o[n][f][r];
        if (c == 0) {
            #pragma unroll
            for (int n = 0; n < 2; ++n)
                #pragma unroll
                for (int r = 0; r < 4; ++r) {
                    mld[(wq * 4 + wk) * 32 + n * 16 + 4 * g + r] = m_o[n][r];
                    lld[(wq * 4 + wk) * 32 + n * 16 + 4 * g + r] = l_o[n][r];
                }
        }
    }
    __syncthreads();

    if (wk == 0) {
        #pragma unroll
        for (int n = 0; n < 2; ++n) {
            #pragma unroll
            for (int r = 0; r < 4; ++r) {
                const int rl = n * 16 + 4 * g + r;
                const float m0 = m_o[n][r];
                const float m1 = mld[(wq * 4 + 1) * 32 + rl];
                const float m2 = mld[(wq * 4 + 2) * 32 + rl];
                const float m3 = mld[(wq * 4 + 3) * 32 + rl];
                const float ms = fmaxf(fmaxf(m0, m1), fmaxf(m2, m3));
                const float a0 = __builtin_amdgcn_exp2f(m0 - ms);
                const float a1 = __builtin_amdgcn_exp2f(m1 - ms);
                const float a2 = __builtin_amdgcn_exp2f(m2 - ms);
                const float a3 = __builtin_amdgcn_exp2f(m3 - ms);
                const float ls = a0 * l_o[n][r]
                               + a1 * lld[(wq * 4 + 1) * 32 + rl]
                               + a2 * lld[(wq * 4 + 2) * 32 + rl]
                               + a3 * lld[(wq * 4 + 3) * 32 + rl];
                const float inv = 1.0f / ls;
                float* orow = out + ((size_t)bb * SEQ + q0 + wq * 32 + rl) * DQK;
                #pragma unroll
                for (int f = 0; f < 8; ++f) {
                    float v = a0 * o[n][f][r]
                            + a1 * olds[(size_t)((wq * 3 + 0) * 32 + rl) * 132 + f * 16 + c]
                            + a2 * olds[(size_t)((wq * 3 + 1) * 32 + rl) * 132 + f * 16 + c]
                            + a3 * olds[(size_t)((wq * 3 + 2) * 32 + rl) * 132 + f * 16 + c];
                    orow[f * 16 + c] = v * inv;
                }
            }
        }
    }
}

extern "C" void kernel_launch(void* const* d_in, const int* in_sizes, int n_in,
                              void* d_out, int out_size, void* d_ws, size_t ws_size,
                              hipStream_t stream) {
    const float* x  = (const float*)d_in[0];
    const float* Wq = (const float*)d_in[1];
    const float* bq = (const float*)d_in[2];
    const float* Wk = (const float*)d_in[3];
    const float* bk = (const float*)d_in[4];
    const float* Wv = (const float*)d_in[5];
    const float* bv = (const float*)d_in[6];
    float* outp = (float*)d_out;

    f16*   qf    = (f16*)d_ws;
    f16*   kf    = qf + (size_t)BATCH * SEQ * DQK;
    f16*   vt    = kf + (size_t)BATCH * SEQ * DQK;
    f16*   wt    = vt + (size_t)BATCH * DQK * SEQ;
    float* biasf = (float*)(wt + (size_t)384 * DM);

    wcvt_kernel<<<24, 256, 0, stream>>>(Wq, bq, Wk, bk, Wv, bv, wt, biasf);

    proj_kernel<<<BATCH * SEQ / 64, 512, 0, stream>>>(x, wt, biasf, qf, kf, vt);

    attn_kernel<<<256, 512, 0, stream>>>(qf, kf, vt, outp);
}

// Round 7
// 158.743 us; speedup vs baseline: 1.0248x; 1.0248x over previous
//
#include <hip/hip_runtime.h>
#include <math.h>

#define DM    1024
#define DQK   128
#define BATCH 4
#define SEQ   4096
// 1/sqrt(128) * log2(e) folded into Wq/bq at wcvt time -> softmax uses exp2 directly
#define QSCALE (0.08838834764831845f * 1.4426950408889634f)
#define DEFER_THR 6.0f

typedef _Float16 f16;
typedef _Float16 f16x4 __attribute__((ext_vector_type(4)));
typedef _Float16 f16x8 __attribute__((ext_vector_type(8)));
typedef float    f32x4 __attribute__((ext_vector_type(4)));

// ---------------- W convert/transpose pre-kernel ----------------
__global__ __launch_bounds__(256) void wcvt_kernel(
    const float* __restrict__ Wq, const float* __restrict__ bq,
    const float* __restrict__ Wk, const float* __restrict__ bk,
    const float* __restrict__ Wv, const float* __restrict__ bv,
    f16* __restrict__ wt, float* __restrict__ biasf)
{
    const int sel = blockIdx.x >> 3;
    const int k0  = (blockIdx.x & 7) * 128;
    const float* W; const float* b; float sc;
    if (sel == 0)      { W = Wq; b = bq; sc = QSCALE; }
    else if (sel == 1) { W = Wk; b = bk; sc = 1.0f; }
    else               { W = Wv; b = bv; sc = 1.0f; }

    __shared__ f16 tile[128][136];

    #pragma unroll
    for (int it = 0; it < 16; ++it) {
        int flat = threadIdx.x + it * 256;
        int kk   = flat >> 5;
        int c4   = flat & 31;
        float4 w4 = *(const float4*)(W + (size_t)(k0 + kk) * DQK + c4 * 4);
        tile[kk][c4 * 4 + 0] = (f16)(w4.x * sc);
        tile[kk][c4 * 4 + 1] = (f16)(w4.y * sc);
        tile[kk][c4 * 4 + 2] = (f16)(w4.z * sc);
        tile[kk][c4 * 4 + 3] = (f16)(w4.w * sc);
    }
    __syncthreads();

    #pragma unroll
    for (int it = 0; it < 8; ++it) {
        int flat = threadIdx.x + it * 256;
        int n    = flat >> 4;
        int kc   = flat & 15;
        f16x8 v;
        #pragma unroll
        for (int i = 0; i < 8; ++i) v[i] = tile[kc * 8 + i][n];
        *(f16x8*)(wt + (size_t)(sel * 128 + n) * DM + k0 + kc * 8) = v;
    }
    if ((blockIdx.x & 7) == 0 && threadIdx.x < 128)
        biasf[sel * 128 + threadIdx.x] = b[threadIdx.x] * sc;
}

// ---------------- Fused QKV projection, f16 MFMA (unchanged) ----------------
__global__ __launch_bounds__(512, 2) void proj_kernel(
    const float* __restrict__ x, const f16* __restrict__ wt,
    const float* __restrict__ biasf,
    f16* __restrict__ qo, f16* __restrict__ ko, f16* __restrict__ vto)
{
    __shared__ __align__(16) unsigned char smem[50176];

    const int tid  = threadIdx.x;
    const int lane = tid & 63;
    const int w    = tid >> 6;
    const int c    = lane & 15;
    const int g    = lane >> 4;
    const int r0   = blockIdx.x * 64;

    const int srow = tid >> 3;
    const int skq  = tid & 7;
    const float* const xsrc  = x + (size_t)(r0 + srow) * DM + skq * 8;
    const unsigned     swoff = (unsigned)(srow * 128 + ((skq ^ (srow & 7)) * 16));

    f32x4 acc[4][3];
    #pragma unroll
    for (int rf = 0; rf < 4; ++rf)
        #pragma unroll
        for (int nf = 0; nf < 3; ++nf) acc[rf][nf] = (f32x4)0.f;

    float4 xa, xb2;
    auto gload = [&](int t) {
        const float* p = xsrc + t * 64;
        xa  = *(const float4*)p;
        xb2 = *(const float4*)(p + 4);
    };
    auto swrite = [&](int buf) {
        f16x8 h;
        h[0] = (f16)xa.x;  h[1] = (f16)xa.y;  h[2] = (f16)xa.z;  h[3] = (f16)xa.w;
        h[4] = (f16)xb2.x; h[5] = (f16)xb2.y; h[6] = (f16)xb2.z; h[7] = (f16)xb2.w;
        *(f16x8*)(smem + (unsigned)buf * 8192u + swoff) = h;
    };

    gload(0); swrite(0);
    gload(1);
    __syncthreads();

    for (int t = 0; t < 16; ++t) {
        const int cur = t & 1;
        if (t < 15) swrite(cur ^ 1);
        if (t < 14) gload(t + 2);

        f16x8 af[4][2];
        #pragma unroll
        for (int rf = 0; rf < 4; ++rf)
            #pragma unroll
            for (int ks = 0; ks < 2; ++ks)
                af[rf][ks] = *(const f16x8*)(smem + (unsigned)cur * 8192u
                    + (unsigned)((rf * 16 + c) * 128)
                    + (unsigned)((((4 * ks + g) ^ (c & 7)) * 16)));

        #pragma unroll
        for (int nf = 0; nf < 3; ++nf) {
            #pragma unroll
            for (int ks = 0; ks < 2; ++ks) {
                f16x8 bf = *(const f16x8*)(wt
                    + (size_t)(w * 48 + nf * 16 + c) * DM + t * 64 + ks * 32 + g * 8);
                #pragma unroll
                for (int rf = 0; rf < 4; ++rf)
                    acc[rf][nf] = __builtin_amdgcn_mfma_f32_16x16x32_f16(
                        af[rf][ks], bf, acc[rf][nf], 0, 0, 0);
            }
        }
        __syncthreads();
    }

    f16* const tile = (f16*)smem;
    #pragma unroll
    for (int rf = 0; rf < 4; ++rf)
        #pragma unroll
        for (int nf = 0; nf < 3; ++nf) {
            const int n  = w * 48 + nf * 16 + c;
            const float bb = biasf[n];
            #pragma unroll
            for (int r = 0; r < 4; ++r) {
                const int row = rf * 16 + 4 * g + r;
                tile[row * 392 + n] = (f16)(acc[rf][nf][r] + bb);
            }
        }
    __syncthreads();

    #pragma unroll
    for (int it = 0; it < 2; ++it) {
        const int u   = tid + it * 512;
        const int row = u >> 4;
        const int c8  = (u & 15) * 8;
        *(f16x8*)(qo + (size_t)(r0 + row) * DQK + c8) = *(const f16x8*)&tile[row * 392 + c8];
        *(f16x8*)(ko + (size_t)(r0 + row) * DQK + c8) = *(const f16x8*)&tile[row * 392 + 128 + c8];
    }
    const int gb = r0 >> 12;
    const int s0 = r0 & (SEQ - 1);
    #pragma unroll
    for (int it = 0; it < 2; ++it) {
        const int u  = tid + it * 512;
        const int d  = u >> 3;
        const int s8 = (u & 7) * 8;
        f16x8 vv;
        #pragma unroll
        for (int i = 0; i < 8; ++i) vv[i] = tile[(s8 + i) * 392 + 256 + d];
        *(f16x8*)(vto + ((size_t)gb * DQK + d) * SEQ + s0 + s8) = vv;
    }
}

// ---------------- Flash attention: 2 blocks/CU via KV-split, single-buffer staging ----------
__device__ __forceinline__ void stage16(const void* g, unsigned char* l) {
    __builtin_amdgcn_global_load_lds(
        (const __attribute__((address_space(1))) unsigned int*)g,
        (__attribute__((address_space(3))) unsigned int*)l, 16, 0, 0);
}

#define KOFF 0u
#define VOFF 32768u
#define MOFF 65536u
#define LOFF 66560u

// SPLIT=1: grid 512, each block does half the keys, writes f16 partials + LSE.
// SPLIT=0: grid 256, full sequence, writes f32 output directly (ws-size fallback).
template<int SPLIT>
__global__ __launch_bounds__(512, 4) void attn_kernel(
    const f16* __restrict__ qg, const f16* __restrict__ kg,
    const f16* __restrict__ vtg, float* __restrict__ out,
    f16* __restrict__ po, float* __restrict__ pL)
{
    __shared__ __align__(16) unsigned char smem[67584];

    const int tid  = threadIdx.x;
    const int lane = tid & 63;
    const int w    = tid >> 6;      // 0..7
    const int wq   = w >> 2;        // 0..1
    const int wk   = w & 3;         // 0..3
    const int c    = lane & 15;
    const int g    = lane >> 4;     // 0..3

    const int bid  = blockIdx.x;
    const int low3 = bid & 7;       // XCD id
    const int bb   = low3 >> 1;     // batch pinned to XCD pair
    int qt, half;
    if (SPLIT) { qt = bid >> 3;                         half = low3 & 1; }
    else       { qt = (bid >> 3) | ((low3 & 1) << 5);   half = 0;        }
    const int q0     = qt * 64;
    const int kvbase = half * (SEQ / 2);
    const int ITERS  = SPLIT ? 16 : 32;

    const f16*  qb = qg  + (size_t)bb * SEQ * DQK;
    const char* kB = (const char*)(kg  + (size_t)bb * SEQ * DQK);
    const char* vB = (const char*)(vtg + (size_t)bb * DQK * SEQ);

    // Q frags (B-operand for swapped QK^T): q = 16n + c, k(d) = ks*32 + 8g + i
    f16x8 qf[2][4];
    {
        const f16* qr = qb + (size_t)(q0 + wq * 32) * DQK;
        #pragma unroll
        for (int n = 0; n < 2; ++n)
            #pragma unroll
            for (int ks = 0; ks < 4; ++ks)
                qf[n][ks] = *(const f16x8*)(qr + (n * 16 + c) * DQK + ks * 32 + 8 * g);
    }

    f32x4 o[2][8];
    #pragma unroll
    for (int n = 0; n < 2; ++n)
        #pragma unroll
        for (int f = 0; f < 8; ++f) o[n][f] = (f32x4)0.f;
    float m_run[2] = {-3e38f, -3e38f};
    float l_run[2] = {0.f, 0.f};

    const unsigned wbase = (unsigned)w * 1024;

    auto stage_tiles = [&](int t) {
        const int kv0 = kvbase + t * 128;
        #pragma unroll
        for (int cc = 0; cc < 4; ++cc) {
            const int j   = tid + cc * 512;
            const int row = j >> 4;
            const int col = j & 15;
            const int sw  = (col ^ (row & 7)) * 16;
            stage16(kB + (size_t)(kv0 + row) * 256 + sw, smem + KOFF + wbase + cc * 8192);
            stage16(vB + (size_t)row * 8192 + (size_t)kv0 * 2 + sw, smem + VOFF + wbase + cc * 8192);
        }
    };

    // bpermute source-lane byte-addresses (loop-invariant)
    const int addr_h0 = (16 * (2 * (g & 1) + 0) + c) * 4;
    const int addr_h1 = (16 * (2 * (g & 1) + 1) + c) * 4;
    const bool hi_m = (g >= 2);

    unsigned char* const kbase = smem + KOFF;
    unsigned char* const vbase = smem + VOFF;

    stage_tiles(0);

    for (int t = 0; t < ITERS; ++t) {
        __syncthreads();   // staged tile landed (drains each wave's global_load_lds)

        // ---- swapped QK^T: S^T[kv 32][q 32], A = K frag, B = Q frag ----
        f32x4 s[2][2];   // [m (kv16)][n (q16)]
        s[0][0] = (f32x4)0.f; s[0][1] = (f32x4)0.f;
        s[1][0] = (f32x4)0.f; s[1][1] = (f32x4)0.f;
        __builtin_amdgcn_s_setprio(1);
        #pragma unroll
        for (int ks = 0; ks < 4; ++ks) {
            #pragma unroll
            for (int m = 0; m < 2; ++m) {
                f16x8 kf = *(const f16x8*)(kbase
                    + (unsigned)(wk * 32 + m * 16 + c) * 256u
                    + (unsigned)(((4 * ks + g) ^ (c & 7)) * 16));
                s[m][0] = __builtin_amdgcn_mfma_f32_16x16x32_f16(kf, qf[0][ks], s[m][0], 0, 0, 0);
                s[m][1] = __builtin_amdgcn_mfma_f32_16x16x32_f16(kf, qf[1][ks], s[m][1], 0, 0, 0);
            }
        }
        __builtin_amdgcn_s_setprio(0);

        // ---- lane-local softmax max (per q-row = 16n + c) ----
        float mt[2];
        #pragma unroll
        for (int n = 0; n < 2; ++n) {
            float a0 = fmaxf(fmaxf(s[0][n][0], s[0][n][1]), fmaxf(s[0][n][2], s[0][n][3]));
            float a1 = fmaxf(fmaxf(s[1][n][0], s[1][n][1]), fmaxf(s[1][n][2], s[1][n][3]));
            float v  = fmaxf(a0, a1);
            v = fmaxf(v, __shfl_xor(v, 16, 64));
            v = fmaxf(v, __shfl_xor(v, 32, 64));
            mt[n] = v;
        }

        bool need = (mt[0] > m_run[0] + DEFER_THR) || (mt[1] > m_run[1] + DEFER_THR);
        if (__any(need)) {
            float al[2];
            #pragma unroll
            for (int n = 0; n < 2; ++n) {
                float mn = fmaxf(m_run[n], mt[n]);
                al[n] = __builtin_amdgcn_exp2f(m_run[n] - mn);
                m_run[n] = mn;
                l_run[n] *= al[n];
            }
            float alo[2][4];
            #pragma unroll
            for (int n = 0; n < 2; ++n)
                #pragma unroll
                for (int r = 0; r < 4; ++r)
                    alo[n][r] = __shfl(al[n], 4 * g + r, 16);
            #pragma unroll
            for (int n = 0; n < 2; ++n)
                #pragma unroll
                for (int f = 0; f < 8; ++f)
                    #pragma unroll
                    for (int r = 0; r < 4; ++r) o[n][f][r] *= alo[n][r];
        }

        // e = exp2(S^T - m); l accumulation
        float e[2][2][4];
        #pragma unroll
        for (int m = 0; m < 2; ++m)
            #pragma unroll
            for (int n = 0; n < 2; ++n)
                #pragma unroll
                for (int r = 0; r < 4; ++r)
                    e[m][n][r] = __builtin_amdgcn_exp2f(s[m][n][r] - m_run[n]);

        #pragma unroll
        for (int n = 0; n < 2; ++n) {
            float ls = ((e[0][n][0] + e[0][n][1]) + (e[0][n][2] + e[0][n][3]))
                     + ((e[1][n][0] + e[1][n][1]) + (e[1][n][2] + e[1][n][3]));
            ls += __shfl_xor(ls, 16, 64);
            ls += __shfl_xor(ls, 32, 64);
            l_run[n] += ls;
        }

        // pack to f16 pairs and exchange to PV A-frag layout via bpermute
        int u[2][2][2];
        #pragma unroll
        for (int n = 0; n < 2; ++n)
            #pragma unroll
            for (int m = 0; m < 2; ++m)
                #pragma unroll
                for (int p = 0; p < 2; ++p) {
                    auto h2 = __builtin_amdgcn_cvt_pkrtz(e[m][n][2 * p], e[m][n][2 * p + 1]);
                    u[n][m][p] = __builtin_bit_cast(int, h2);
                }

        f16x8 pa[2];
        #pragma unroll
        for (int n = 0; n < 2; ++n) {
            int paw[4];
            #pragma unroll
            for (int j = 0; j < 4; ++j) {
                const int addr = (j >> 1) ? addr_h1 : addr_h0;
                int tA = __builtin_amdgcn_ds_bpermute(addr, u[n][0][j & 1]);
                int tB = __builtin_amdgcn_ds_bpermute(addr, u[n][1][j & 1]);
                paw[j] = hi_m ? tB : tA;
            }
            int4 pw = make_int4(paw[0], paw[1], paw[2], paw[3]);
            pa[n] = __builtin_bit_cast(f16x8, pw);
        }

        // ---- PV: O[32 q][128 d] += P * V ----
        __builtin_amdgcn_s_setprio(1);
        #pragma unroll
        for (int df = 0; df < 8; ++df) {
            f16x8 vf = *(const f16x8*)(vbase
                + (unsigned)(df * 16 + c) * 256u
                + (unsigned)(((4 * wk + g) ^ (c & 7)) * 16));
            o[0][df] = __builtin_amdgcn_mfma_f32_16x16x32_f16(pa[0], vf, o[0][df], 0, 0, 0);
            o[1][df] = __builtin_amdgcn_mfma_f32_16x16x32_f16(pa[1], vf, o[1][df], 0, 0, 0);
        }
        __builtin_amdgcn_s_setprio(0);

        __syncthreads();   // all LDS reads of this tile complete
        if (t + 1 < ITERS) stage_tiles(t + 1);
    }

    // ship m, l to O row domain (q = 16n + 4g + r)
    float m_o[2][4], l_o[2][4];
    #pragma unroll
    for (int n = 0; n < 2; ++n)
        #pragma unroll
        for (int r = 0; r < 4; ++r) {
            m_o[n][r] = __shfl(m_run[n], 4 * g + r, 16);
            l_o[n][r] = __shfl(l_run[n], 4 * g + r, 16);
        }

    float* const mld  = (float*)(smem + MOFF);
    float* const lld  = (float*)(smem + LOFF);
    float* const olds = (float*)smem;   // 64 rows x 132 f32 = 33.8 KB, reuses staging

    // publish m,l
    if (c == 0) {
        #pragma unroll
        for (int n = 0; n < 2; ++n)
            #pragma unroll
            for (int r = 0; r < 4; ++r) {
                mld[w * 32 + n * 16 + 4 * g + r] = m_o[n][r];
                lld[w * 32 + n * 16 + 4 * g + r] = l_o[n][r];
            }
    }
    __syncthreads();

    float ms_s[2][4], lt_s[2][4];
    if (wk == 0) {
        #pragma unroll
        for (int n = 0; n < 2; ++n)
            #pragma unroll
            for (int r = 0; r < 4; ++r) {
                const int rl = n * 16 + 4 * g + r;
                float mm = m_o[n][r];
                #pragma unroll
                for (int i = 1; i < 4; ++i) mm = fmaxf(mm, mld[(wq * 4 + i) * 32 + rl]);
                ms_s[n][r] = mm;
                float a0 = __builtin_amdgcn_exp2f(m_o[n][r] - mm);
                float lt = a0 * l_o[n][r];
                #pragma unroll
                for (int i = 1; i < 4; ++i)
                    lt += __builtin_amdgcn_exp2f(mld[(wq * 4 + i) * 32 + rl] - mm)
                          * lld[(wq * 4 + i) * 32 + rl];
                lt_s[n][r] = lt;
                #pragma unroll
                for (int f = 0; f < 8; ++f) o[n][f][r] *= a0;
            }
    }

    // 3-phase accumulation through the 34 KB buffer
    for (int ph = 1; ph < 4; ++ph) {
        if (wk == ph) {
            #pragma unroll
            for (int n = 0; n < 2; ++n)
                #pragma unroll
                for (int f = 0; f < 8; ++f)
                    #pragma unroll
                    for (int r = 0; r < 4; ++r)
                        olds[(size_t)(wq * 32 + n * 16 + 4 * g + r) * 132 + f * 16 + c] = o[n][f][r];
        }
        __syncthreads();
        if (wk == 0) {
            #pragma unroll
            for (int n = 0; n < 2; ++n)
                #pragma unroll
                for (int r = 0; r < 4; ++r) {
                    const int rl = n * 16 + 4 * g + r;
                    const float ai = __builtin_amdgcn_exp2f(mld[(wq * 4 + ph) * 32 + rl] - ms_s[n][r]);
                    #pragma unroll
                    for (int f = 0; f < 8; ++f)
                        o[n][f][r] += ai * olds[(size_t)(wq * 32 + rl) * 132 + f * 16 + c];
                }
        }
        __syncthreads();
    }

    if (wk == 0) {
        #pragma unroll
        for (int n = 0; n < 2; ++n)
            #pragma unroll
            for (int r = 0; r < 4; ++r) {
                const int rl = n * 16 + 4 * g + r;
                const int q  = q0 + wq * 32 + rl;
                const float inv = 1.0f / lt_s[n][r];
                if (SPLIT) {
                    f16* prow = po + ((size_t)(half * BATCH + bb) * SEQ + q) * DQK;
                    #pragma unroll
                    for (int f = 0; f < 8; ++f)
                        prow[f * 16 + c] = (f16)(o[n][f][r] * inv);
                    if (c == 0)
                        pL[(size_t)(half * BATCH + bb) * SEQ + q]
                            = ms_s[n][r] + __builtin_amdgcn_logf(lt_s[n][r]);
                } else {
                    float* orow = out + ((size_t)bb * SEQ + q) * DQK;
                    #pragma unroll
                    for (int f = 0; f < 8; ++f)
                        orow[f * 16 + c] = o[n][f][r] * inv;
                }
            }
    }
}

// ---------------- LSE merge of the two KV halves ----------------
__global__ __launch_bounds__(256) void merge_kernel(
    const f16* __restrict__ po, const float* __restrict__ pL, float* __restrict__ out)
{
    const int gid = blockIdx.x * 256 + threadIdx.x;   // 0..262143
    const int q   = gid >> 4;                          // 0..16383 (= b*4096 + row)
    const int d0  = (gid & 15) * 8;
    const float L0 = pL[q];
    const float L1 = pL[BATCH * SEQ + q];
    const float Lm = fmaxf(L0, L1);
    const float w0 = __builtin_amdgcn_exp2f(L0 - Lm);
    const float w1 = __builtin_amdgcn_exp2f(L1 - Lm);
    const float inv = 1.0f / (w0 + w1);
    f16x8 a  = *(const f16x8*)(po + (size_t)q * DQK + d0);
    f16x8 b2 = *(const f16x8*)(po + ((size_t)BATCH * SEQ + q) * DQK + d0);
    float4 o0, o1;
    o0.x = (w0 * (float)a[0] + w1 * (float)b2[0]) * inv;
    o0.y = (w0 * (float)a[1] + w1 * (float)b2[1]) * inv;
    o0.z = (w0 * (float)a[2] + w1 * (float)b2[2]) * inv;
    o0.w = (w0 * (float)a[3] + w1 * (float)b2[3]) * inv;
    o1.x = (w0 * (float)a[4] + w1 * (float)b2[4]) * inv;
    o1.y = (w0 * (float)a[5] + w1 * (float)b2[5]) * inv;
    o1.z = (w0 * (float)a[6] + w1 * (float)b2[6]) * inv;
    o1.w = (w0 * (float)a[7] + w1 * (float)b2[7]) * inv;
    *(float4*)(out + (size_t)q * DQK + d0)     = o0;
    *(float4*)(out + (size_t)q * DQK + d0 + 4) = o1;
}

extern "C" void kernel_launch(void* const* d_in, const int* in_sizes, int n_in,
                              void* d_out, int out_size, void* d_ws, size_t ws_size,
                              hipStream_t stream) {
    const float* x  = (const float*)d_in[0];
    const float* Wq = (const float*)d_in[1];
    const float* bq = (const float*)d_in[2];
    const float* Wk = (const float*)d_in[3];
    const float* bk = (const float*)d_in[4];
    const float* Wv = (const float*)d_in[5];
    const float* bv = (const float*)d_in[6];
    float* outp = (float*)d_out;

    char* ws = (char*)d_ws;
    const size_t SZQKV = (size_t)BATCH * SEQ * DQK * sizeof(f16);   // 4 MB each
    f16*   qf    = (f16*)(ws);
    f16*   kf    = (f16*)(ws + SZQKV);
    f16*   vt    = (f16*)(ws + 2 * SZQKV);
    f16*   wt    = (f16*)(ws + 3 * SZQKV);                          // 768 KB
    float* biasf = (float*)(ws + 3 * SZQKV + 786432);               // 1.5 KB
    char*  pbase = ws + 3 * SZQKV + 786432 + 1536;                  // 16B-aligned
    f16*   po    = (f16*)pbase;                                     // 8 MB
    float* pL    = (float*)(pbase + (size_t)2 * BATCH * SEQ * DQK * sizeof(f16));  // 128 KB
    const size_t need = (size_t)(pL + 2 * BATCH * SEQ) - (size_t)d_ws + (size_t)(pL - (float*)0) * 0
                        ;
    const size_t need_bytes = ((char*)(pL + 2 * BATCH * SEQ)) - ws;

    wcvt_kernel<<<24, 256, 0, stream>>>(Wq, bq, Wk, bk, Wv, bv, wt, biasf);

    proj_kernel<<<BATCH * SEQ / 64, 512, 0, stream>>>(x, wt, biasf, qf, kf, vt);

    if (ws_size >= need_bytes) {
        attn_kernel<1><<<512, 512, 0, stream>>>(qf, kf, vt, outp, po, pL);
        merge_kernel<<<BATCH * SEQ * DQK / 8 / 256, 256, 0, stream>>>(po, pL, outp);
    } else {
        attn_kernel<0><<<256, 512, 0, stream>>>(qf, kf, vt, outp, po, pL);
    }
    (void)need;
}

// Round 8
// 130.980 us; speedup vs baseline: 1.2420x; 1.2120x over previous
//
#include <hip/hip_runtime.h>
#include <math.h>

#define DM    1024
#define DQK   128
#define BATCH 4
#define SEQ   4096
// 1/sqrt(128) * log2(e) folded into Wq/bq at wcvt time -> softmax uses exp2 directly
#define QSCALE (0.08838834764831845f * 1.4426950408889634f)
#define DEFER_THR 6.0f

typedef _Float16 f16;
typedef _Float16 f16x4 __attribute__((ext_vector_type(4)));
typedef _Float16 f16x8 __attribute__((ext_vector_type(8)));
typedef float    f32x4 __attribute__((ext_vector_type(4)));

// ---------------- W convert/transpose pre-kernel ----------------
__global__ __launch_bounds__(256) void wcvt_kernel(
    const float* __restrict__ Wq, const float* __restrict__ bq,
    const float* __restrict__ Wk, const float* __restrict__ bk,
    const float* __restrict__ Wv, const float* __restrict__ bv,
    f16* __restrict__ wt, float* __restrict__ biasf)
{
    const int sel = blockIdx.x >> 3;
    const int k0  = (blockIdx.x & 7) * 128;
    const float* W; const float* b; float sc;
    if (sel == 0)      { W = Wq; b = bq; sc = QSCALE; }
    else if (sel == 1) { W = Wk; b = bk; sc = 1.0f; }
    else               { W = Wv; b = bv; sc = 1.0f; }

    __shared__ f16 tile[128][136];

    #pragma unroll
    for (int it = 0; it < 16; ++it) {
        int flat = threadIdx.x + it * 256;
        int kk   = flat >> 5;
        int c4   = flat & 31;
        float4 w4 = *(const float4*)(W + (size_t)(k0 + kk) * DQK + c4 * 4);
        tile[kk][c4 * 4 + 0] = (f16)(w4.x * sc);
        tile[kk][c4 * 4 + 1] = (f16)(w4.y * sc);
        tile[kk][c4 * 4 + 2] = (f16)(w4.z * sc);
        tile[kk][c4 * 4 + 3] = (f16)(w4.w * sc);
    }
    __syncthreads();

    #pragma unroll
    for (int it = 0; it < 8; ++it) {
        int flat = threadIdx.x + it * 256;
        int n    = flat >> 4;
        int kc   = flat & 15;
        f16x8 v;
        #pragma unroll
        for (int i = 0; i < 8; ++i) v[i] = tile[kc * 8 + i][n];
        *(f16x8*)(wt + (size_t)(sel * 128 + n) * DM + k0 + kc * 8) = v;
    }
    if ((blockIdx.x & 7) == 0 && threadIdx.x < 128)
        biasf[sel * 128 + threadIdx.x] = b[threadIdx.x] * sc;
}

// ---------------- Fused QKV projection, f16 MFMA (unchanged) ----------------
__global__ __launch_bounds__(512, 2) void proj_kernel(
    const float* __restrict__ x, const f16* __restrict__ wt,
    const float* __restrict__ biasf,
    f16* __restrict__ qo, f16* __restrict__ ko, f16* __restrict__ vto)
{
    __shared__ __align__(16) unsigned char smem[50176];

    const int tid  = threadIdx.x;
    const int lane = tid & 63;
    const int w    = tid >> 6;
    const int c    = lane & 15;
    const int g    = lane >> 4;
    const int r0   = blockIdx.x * 64;

    const int srow = tid >> 3;
    const int skq  = tid & 7;
    const float* const xsrc  = x + (size_t)(r0 + srow) * DM + skq * 8;
    const unsigned     swoff = (unsigned)(srow * 128 + ((skq ^ (srow & 7)) * 16));

    f32x4 acc[4][3];
    #pragma unroll
    for (int rf = 0; rf < 4; ++rf)
        #pragma unroll
        for (int nf = 0; nf < 3; ++nf) acc[rf][nf] = (f32x4)0.f;

    float4 xa, xb2;
    auto gload = [&](int t) {
        const float* p = xsrc + t * 64;
        xa  = *(const float4*)p;
        xb2 = *(const float4*)(p + 4);
    };
    auto swrite = [&](int buf) {
        f16x8 h;
        h[0] = (f16)xa.x;  h[1] = (f16)xa.y;  h[2] = (f16)xa.z;  h[3] = (f16)xa.w;
        h[4] = (f16)xb2.x; h[5] = (f16)xb2.y; h[6] = (f16)xb2.z; h[7] = (f16)xb2.w;
        *(f16x8*)(smem + (unsigned)buf * 8192u + swoff) = h;
    };

    gload(0); swrite(0);
    gload(1);
    __syncthreads();

    for (int t = 0; t < 16; ++t) {
        const int cur = t & 1;
        if (t < 15) swrite(cur ^ 1);
        if (t < 14) gload(t + 2);

        f16x8 af[4][2];
        #pragma unroll
        for (int rf = 0; rf < 4; ++rf)
            #pragma unroll
            for (int ks = 0; ks < 2; ++ks)
                af[rf][ks] = *(const f16x8*)(smem + (unsigned)cur * 8192u
                    + (unsigned)((rf * 16 + c) * 128)
                    + (unsigned)((((4 * ks + g) ^ (c & 7)) * 16)));

        #pragma unroll
        for (int nf = 0; nf < 3; ++nf) {
            #pragma unroll
            for (int ks = 0; ks < 2; ++ks) {
                f16x8 bf = *(const f16x8*)(wt
                    + (size_t)(w * 48 + nf * 16 + c) * DM + t * 64 + ks * 32 + g * 8);
                #pragma unroll
                for (int rf = 0; rf < 4; ++rf)
                    acc[rf][nf] = __builtin_amdgcn_mfma_f32_16x16x32_f16(
                        af[rf][ks], bf, acc[rf][nf], 0, 0, 0);
            }
        }
        __syncthreads();
    }

    f16* const tile = (f16*)smem;
    #pragma unroll
    for (int rf = 0; rf < 4; ++rf)
        #pragma unroll
        for (int nf = 0; nf < 3; ++nf) {
            const int n  = w * 48 + nf * 16 + c;
            const float bb = biasf[n];
            #pragma unroll
            for (int r = 0; r < 4; ++r) {
                const int row = rf * 16 + 4 * g + r;
                tile[row * 392 + n] = (f16)(acc[rf][nf][r] + bb);
            }
        }
    __syncthreads();

    #pragma unroll
    for (int it = 0; it < 2; ++it) {
        const int u   = tid + it * 512;
        const int row = u >> 4;
        const int c8  = (u & 15) * 8;
        *(f16x8*)(qo + (size_t)(r0 + row) * DQK + c8) = *(const f16x8*)&tile[row * 392 + c8];
        *(f16x8*)(ko + (size_t)(r0 + row) * DQK + c8) = *(const f16x8*)&tile[row * 392 + 128 + c8];
    }
    const int gb = r0 >> 12;
    const int s0 = r0 & (SEQ - 1);
    #pragma unroll
    for (int it = 0; it < 2; ++it) {
        const int u  = tid + it * 512;
        const int d  = u >> 3;
        const int s8 = (u & 7) * 8;
        f16x8 vv;
        #pragma unroll
        for (int i = 0; i < 8; ++i) vv[i] = tile[(s8 + i) * 392 + 256 + d];
        *(f16x8*)(vto + ((size_t)gb * DQK + d) * SEQ + s0 + s8) = vv;
    }
}

// ---------------- Flash attention: round-4 schedule, K staged in LDS, V direct from L2 ----
__device__ __forceinline__ void stage16(const void* g, unsigned char* l) {
    __builtin_amdgcn_global_load_lds(
        (const __attribute__((address_space(1))) unsigned int*)g,
        (__attribute__((address_space(3))) unsigned int*)l, 16, 0, 0);
}

#define KOFF 0u        // 2 x 32 KB K double buffer
#define MOFF 65536u
#define LOFF 66560u

__global__ __launch_bounds__(512, 2) void attn_kernel(
    const f16* __restrict__ qg, const f16* __restrict__ kg,
    const f16* __restrict__ vtg, float* __restrict__ out)
{
    __shared__ __align__(16) unsigned char smem[67584];

    const int tid  = threadIdx.x;
    const int lane = tid & 63;
    const int w    = tid >> 6;      // 0..7
    const int wq   = w >> 2;        // 0..1
    const int wk   = w & 3;         // 0..3
    const int c    = lane & 15;
    const int g    = lane >> 4;     // 0..3

    const int bid = blockIdx.x;
    const int xcd = bid & 7;
    const int bb  = xcd >> 1;       // batch pinned to XCD pair (L2-resident K/V)
    const int qt  = (bid >> 3) | ((xcd & 1) << 5);
    const int q0  = qt * 64;

    const f16*  qb = qg  + (size_t)bb * SEQ * DQK;
    const char* kB = (const char*)(kg  + (size_t)bb * SEQ * DQK);
    const char* vB = (const char*)(vtg + (size_t)bb * DQK * SEQ);

    // per-lane base for direct V^T fragment loads: d-row = df*16 + c, kv-chunk = wk*32 + g*8
    const char* const vlane = vB + (size_t)c * (SEQ * 2) + (wk * 32 + g * 8) * 2;

    // Q frags (B-operand for swapped QK^T): q = 16n + c, k(d) = ks*32 + 8g + i
    f16x8 qf[2][4];
    {
        const f16* qr = qb + (size_t)(q0 + wq * 32) * DQK;
        #pragma unroll
        for (int n = 0; n < 2; ++n)
            #pragma unroll
            for (int ks = 0; ks < 4; ++ks)
                qf[n][ks] = *(const f16x8*)(qr + (n * 16 + c) * DQK + ks * 32 + 8 * g);
    }

    f32x4 o[2][8];
    #pragma unroll
    for (int n = 0; n < 2; ++n)
        #pragma unroll
        for (int f = 0; f < 8; ++f) o[n][f] = (f32x4)0.f;
    float m_run[2] = {-3e38f, -3e38f};
    float l_run[2] = {0.f, 0.f};

    const unsigned wbase = (unsigned)w * 1024;

    auto stage_K = [&](int t, int pbuf) {
        const int kv0 = t * 128;
        unsigned char* kdst = smem + KOFF + (unsigned)pbuf * 32768u + wbase;
        #pragma unroll
        for (int cc = 0; cc < 4; ++cc) {
            const int j   = tid + cc * 512;
            const int row = j >> 4;
            const int col = j & 15;
            const int sw  = (col ^ (row & 7)) * 16;
            stage16(kB + (size_t)(kv0 + row) * 256 + sw, kdst + cc * 8192);
        }
    };

    // bpermute source-lane byte-addresses (loop-invariant)
    const int addr_h0 = (16 * (2 * (g & 1) + 0) + c) * 4;
    const int addr_h1 = (16 * (2 * (g & 1) + 1) + c) * 4;
    const bool hi_m = (g >= 2);

    stage_K(0, 0);
    __syncthreads();   // tile 0 ready

    for (int t = 0; t < 32; ++t) {
        const int pb = t & 1;
        unsigned char* const kbase = smem + KOFF + (unsigned)pb * 32768u;

        // ---- V frags for THIS tile: issue first (retire at vmcnt(4), used after softmax) ----
        f16x8 vr[8];
        #pragma unroll
        for (int df = 0; df < 8; ++df)
            vr[df] = *(const f16x8*)(vlane + (size_t)t * 256 + (size_t)df * (16 * SEQ * 2));

        if (t < 31) stage_K(t + 1, pb ^ 1);   // K prefetch, drains at end-of-iter barrier

        // ---- swapped QK^T: S^T[kv 32][q 32], A = K frag (LDS), B = Q frag (reg) ----
        f32x4 s[2][2];   // [m (kv16)][n (q16)]
        s[0][0] = (f32x4)0.f; s[0][1] = (f32x4)0.f;
        s[1][0] = (f32x4)0.f; s[1][1] = (f32x4)0.f;
        __builtin_amdgcn_s_setprio(1);
        #pragma unroll
        for (int ks = 0; ks < 4; ++ks) {
            #pragma unroll
            for (int m = 0; m < 2; ++m) {
                f16x8 kf = *(const f16x8*)(kbase
                    + (unsigned)(wk * 32 + m * 16 + c) * 256u
                    + (unsigned)(((4 * ks + g) ^ (c & 7)) * 16));
                s[m][0] = __builtin_amdgcn_mfma_f32_16x16x32_f16(kf, qf[0][ks], s[m][0], 0, 0, 0);
                s[m][1] = __builtin_amdgcn_mfma_f32_16x16x32_f16(kf, qf[1][ks], s[m][1], 0, 0, 0);
            }
        }
        __builtin_amdgcn_s_setprio(0);

        // ---- lane-local softmax max (per q-row = 16n + c) ----
        float mt[2];
        #pragma unroll
        for (int n = 0; n < 2; ++n) {
            float a0 = fmaxf(fmaxf(s[0][n][0], s[0][n][1]), fmaxf(s[0][n][2], s[0][n][3]));
            float a1 = fmaxf(fmaxf(s[1][n][0], s[1][n][1]), fmaxf(s[1][n][2], s[1][n][3]));
            float v  = fmaxf(a0, a1);
            v = fmaxf(v, __shfl_xor(v, 16, 64));
            v = fmaxf(v, __shfl_xor(v, 32, 64));
            mt[n] = v;
        }

        bool need = (mt[0] > m_run[0] + DEFER_THR) || (mt[1] > m_run[1] + DEFER_THR);
        if (__any(need)) {
            float al[2];
            #pragma unroll
            for (int n = 0; n < 2; ++n) {
                float mn = fmaxf(m_run[n], mt[n]);
                al[n] = __builtin_amdgcn_exp2f(m_run[n] - mn);
                m_run[n] = mn;
                l_run[n] *= al[n];
            }
            float alo[2][4];
            #pragma unroll
            for (int n = 0; n < 2; ++n)
                #pragma unroll
                for (int r = 0; r < 4; ++r)
                    alo[n][r] = __shfl(al[n], 4 * g + r, 16);
            #pragma unroll
            for (int n = 0; n < 2; ++n)
                #pragma unroll
                for (int f = 0; f < 8; ++f)
                    #pragma unroll
                    for (int r = 0; r < 4; ++r) o[n][f][r] *= alo[n][r];
        }

        // e = exp2(S^T - m) in place; l accumulation via VALU + 2 shuffles
        #pragma unroll
        for (int m = 0; m < 2; ++m)
            #pragma unroll
            for (int n = 0; n < 2; ++n)
                #pragma unroll
                for (int r = 0; r < 4; ++r)
                    s[m][n][r] = __builtin_amdgcn_exp2f(s[m][n][r] - m_run[n]);

        #pragma unroll
        for (int n = 0; n < 2; ++n) {
            float ls = ((s[0][n][0] + s[0][n][1]) + (s[0][n][2] + s[0][n][3]))
                     + ((s[1][n][0] + s[1][n][1]) + (s[1][n][2] + s[1][n][3]));
            ls += __shfl_xor(ls, 16, 64);
            ls += __shfl_xor(ls, 32, 64);
            l_run[n] += ls;
        }

        // pack to f16 pairs and exchange to PV A-frag layout via bpermute
        int u[2][2][2];
        #pragma unroll
        for (int n = 0; n < 2; ++n)
            #pragma unroll
            for (int m = 0; m < 2; ++m)
                #pragma unroll
                for (int p = 0; p < 2; ++p) {
                    auto h2 = __builtin_amdgcn_cvt_pkrtz(s[m][n][2 * p], s[m][n][2 * p + 1]);
                    u[n][m][p] = __builtin_bit_cast(int, h2);
                }

        f16x8 pa[2];
        #pragma unroll
        for (int n = 0; n < 2; ++n) {
            int paw[4];
            #pragma unroll
            for (int j = 0; j < 4; ++j) {
                const int addr = (j >> 1) ? addr_h1 : addr_h0;
                int tA = __builtin_amdgcn_ds_bpermute(addr, u[n][0][j & 1]);
                int tB = __builtin_amdgcn_ds_bpermute(addr, u[n][1][j & 1]);
                paw[j] = hi_m ? tB : tA;
            }
            int4 pw = make_int4(paw[0], paw[1], paw[2], paw[3]);
            pa[n] = __builtin_bit_cast(f16x8, pw);
        }

        // ---- PV: O[32 q][128 d] += P * V (V frags from registers) ----
        __builtin_amdgcn_s_setprio(1);
        #pragma unroll
        for (int df = 0; df < 8; ++df) {
            o[0][df] = __builtin_amdgcn_mfma_f32_16x16x32_f16(pa[0], vr[df], o[0][df], 0, 0, 0);
            o[1][df] = __builtin_amdgcn_mfma_f32_16x16x32_f16(pa[1], vr[df], o[1][df], 0, 0, 0);
        }
        __builtin_amdgcn_s_setprio(0);

        __syncthreads();   // K(t) reads done everywhere; K(t+1) staged
    }

    // ship m, l to O row domain (q = 16n + 4g + r)
    float m_o[2][4], l_o[2][4];
    #pragma unroll
    for (int n = 0; n < 2; ++n)
        #pragma unroll
        for (int r = 0; r < 4; ++r) {
            m_o[n][r] = __shfl(m_run[n], 4 * g + r, 16);
            l_o[n][r] = __shfl(l_run[n], 4 * g + r, 16);
        }

    float* const mld  = (float*)(smem + MOFF);
    float* const lld  = (float*)(smem + LOFF);
    float* const olds = (float*)smem;   // 64 rows x 132 f32 = 33.8 KB, reuses K staging

    // publish m,l
    if (c == 0) {
        #pragma unroll
        for (int n = 0; n < 2; ++n)
            #pragma unroll
            for (int r = 0; r < 4; ++r) {
                mld[w * 32 + n * 16 + 4 * g + r] = m_o[n][r];
                lld[w * 32 + n * 16 + 4 * g + r] = l_o[n][r];
            }
    }
    __syncthreads();

    float ms_s[2][4], lt_s[2][4];
    if (wk == 0) {
        #pragma unroll
        for (int n = 0; n < 2; ++n)
            #pragma unroll
            for (int r = 0; r < 4; ++r) {
                const int rl = n * 16 + 4 * g + r;
                float mm = m_o[n][r];
                #pragma unroll
                for (int i = 1; i < 4; ++i) mm = fmaxf(mm, mld[(wq * 4 + i) * 32 + rl]);
                ms_s[n][r] = mm;
                float a0 = __builtin_amdgcn_exp2f(m_o[n][r] - mm);
                float lt = a0 * l_o[n][r];
                #pragma unroll
                for (int i = 1; i < 4; ++i)
                    lt += __builtin_amdgcn_exp2f(mld[(wq * 4 + i) * 32 + rl] - mm)
                          * lld[(wq * 4 + i) * 32 + rl];
                lt_s[n][r] = lt;
                #pragma unroll
                for (int f = 0; f < 8; ++f) o[n][f][r] *= a0;
            }
    }

    // 3-phase accumulation through the 34 KB buffer
    for (int ph = 1; ph < 4; ++ph) {
        if (wk == ph) {
            #pragma unroll
            for (int n = 0; n < 2; ++n)
                #pragma unroll
                for (int f = 0; f < 8; ++f)
                    #pragma unroll
                    for (int r = 0; r < 4; ++r)
                        olds[(size_t)(wq * 32 + n * 16 + 4 * g + r) * 132 + f * 16 + c] = o[n][f][r];
        }
        __syncthreads();
        if (wk == 0) {
            #pragma unroll
            for (int n = 0; n < 2; ++n)
                #pragma unroll
                for (int r = 0; r < 4; ++r) {
                    const int rl = n * 16 + 4 * g + r;
                    const float ai = __builtin_amdgcn_exp2f(mld[(wq * 4 + ph) * 32 + rl] - ms_s[n][r]);
                    #pragma unroll
                    for (int f = 0; f < 8; ++f)
                        o[n][f][r] += ai * olds[(size_t)(wq * 32 + rl) * 132 + f * 16 + c];
                }
        }
        __syncthreads();
    }

    if (wk == 0) {
        #pragma unroll
        for (int n = 0; n < 2; ++n)
            #pragma unroll
            for (int r = 0; r < 4; ++r) {
                const int rl = n * 16 + 4 * g + r;
                const int q  = q0 + wq * 32 + rl;
                const float inv = 1.0f / lt_s[n][r];
                float* orow = out + ((size_t)bb * SEQ + q) * DQK;
                #pragma unroll
                for (int f = 0; f < 8; ++f)
                    orow[f * 16 + c] = o[n][f][r] * inv;
            }
    }
}

extern "C" void kernel_launch(void* const* d_in, const int* in_sizes, int n_in,
                              void* d_out, int out_size, void* d_ws, size_t ws_size,
                              hipStream_t stream) {
    const float* x  = (const float*)d_in[0];
    const float* Wq = (const float*)d_in[1];
    const float* bq = (const float*)d_in[2];
    const float* Wk = (const float*)d_in[3];
    const float* bk = (const float*)d_in[4];
    const float* Wv = (const float*)d_in[5];
    const float* bv = (const float*)d_in[6];
    float* outp = (float*)d_out;

    f16*   qf    = (f16*)d_ws;
    f16*   kf    = qf + (size_t)BATCH * SEQ * DQK;
    f16*   vt    = kf + (size_t)BATCH * SEQ * DQK;
    f16*   wt    = vt + (size_t)BATCH * DQK * SEQ;
    float* biasf = (float*)(wt + (size_t)384 * DM);

    wcvt_kernel<<<24, 256, 0, stream>>>(Wq, bq, Wk, bk, Wv, bv, wt, biasf);

    proj_kernel<<<BATCH * SEQ / 64, 512, 0, stream>>>(x, wt, biasf, qf, kf, vt);

    attn_kernel<<<256, 512, 0, stream>>>(qf, kf, vt, outp);
}

// Round 9
// 111.302 us; speedup vs baseline: 1.4615x; 1.1768x over previous
//
#include <hip/hip_runtime.h>
#include <math.h>

#define DM    1024
#define DQK   128
#define BATCH 4
#define SEQ   4096
// 1/sqrt(128) * log2(e) folded into Wq/bq at wcvt time -> softmax uses exp2 directly
#define QSCALE (0.08838834764831845f * 1.4426950408889634f)
#define DEFER_THR 6.0f

typedef _Float16 f16;
typedef _Float16 f16x4 __attribute__((ext_vector_type(4)));
typedef _Float16 f16x8 __attribute__((ext_vector_type(8)));
typedef float    f32x4 __attribute__((ext_vector_type(4)));

// ---------------- W convert/transpose pre-kernel ----------------
__global__ __launch_bounds__(256) void wcvt_kernel(
    const float* __restrict__ Wq, const float* __restrict__ bq,
    const float* __restrict__ Wk, const float* __restrict__ bk,
    const float* __restrict__ Wv, const float* __restrict__ bv,
    f16* __restrict__ wt, float* __restrict__ biasf)
{
    const int sel = blockIdx.x >> 3;
    const int k0  = (blockIdx.x & 7) * 128;
    const float* W; const float* b; float sc;
    if (sel == 0)      { W = Wq; b = bq; sc = QSCALE; }
    else if (sel == 1) { W = Wk; b = bk; sc = 1.0f; }
    else               { W = Wv; b = bv; sc = 1.0f; }

    __shared__ f16 tile[128][136];

    #pragma unroll
    for (int it = 0; it < 16; ++it) {
        int flat = threadIdx.x + it * 256;
        int kk   = flat >> 5;
        int c4   = flat & 31;
        float4 w4 = *(const float4*)(W + (size_t)(k0 + kk) * DQK + c4 * 4);
        tile[kk][c4 * 4 + 0] = (f16)(w4.x * sc);
        tile[kk][c4 * 4 + 1] = (f16)(w4.y * sc);
        tile[kk][c4 * 4 + 2] = (f16)(w4.z * sc);
        tile[kk][c4 * 4 + 3] = (f16)(w4.w * sc);
    }
    __syncthreads();

    #pragma unroll
    for (int it = 0; it < 8; ++it) {
        int flat = threadIdx.x + it * 256;
        int n    = flat >> 4;
        int kc   = flat & 15;
        f16x8 v;
        #pragma unroll
        for (int i = 0; i < 8; ++i) v[i] = tile[kc * 8 + i][n];
        *(f16x8*)(wt + (size_t)(sel * 128 + n) * DM + k0 + kc * 8) = v;
    }
    if ((blockIdx.x & 7) == 0 && threadIdx.x < 128)
        biasf[sel * 128 + threadIdx.x] = b[threadIdx.x] * sc;
}

// ---------------- Fused QKV projection, f16 MFMA (unchanged) ----------------
__global__ __launch_bounds__(512, 2) void proj_kernel(
    const float* __restrict__ x, const f16* __restrict__ wt,
    const float* __restrict__ biasf,
    f16* __restrict__ qo, f16* __restrict__ ko, f16* __restrict__ vto)
{
    __shared__ __align__(16) unsigned char smem[50176];

    const int tid  = threadIdx.x;
    const int lane = tid & 63;
    const int w    = tid >> 6;
    const int c    = lane & 15;
    const int g    = lane >> 4;
    const int r0   = blockIdx.x * 64;

    const int srow = tid >> 3;
    const int skq  = tid & 7;
    const float* const xsrc  = x + (size_t)(r0 + srow) * DM + skq * 8;
    const unsigned     swoff = (unsigned)(srow * 128 + ((skq ^ (srow & 7)) * 16));

    f32x4 acc[4][3];
    #pragma unroll
    for (int rf = 0; rf < 4; ++rf)
        #pragma unroll
        for (int nf = 0; nf < 3; ++nf) acc[rf][nf] = (f32x4)0.f;

    float4 xa, xb2;
    auto gload = [&](int t) {
        const float* p = xsrc + t * 64;
        xa  = *(const float4*)p;
        xb2 = *(const float4*)(p + 4);
    };
    auto swrite = [&](int buf) {
        f16x8 h;
        h[0] = (f16)xa.x;  h[1] = (f16)xa.y;  h[2] = (f16)xa.z;  h[3] = (f16)xa.w;
        h[4] = (f16)xb2.x; h[5] = (f16)xb2.y; h[6] = (f16)xb2.z; h[7] = (f16)xb2.w;
        *(f16x8*)(smem + (unsigned)buf * 8192u + swoff) = h;
    };

    gload(0); swrite(0);
    gload(1);
    __syncthreads();

    for (int t = 0; t < 16; ++t) {
        const int cur = t & 1;
        if (t < 15) swrite(cur ^ 1);
        if (t < 14) gload(t + 2);

        f16x8 af[4][2];
        #pragma unroll
        for (int rf = 0; rf < 4; ++rf)
            #pragma unroll
            for (int ks = 0; ks < 2; ++ks)
                af[rf][ks] = *(const f16x8*)(smem + (unsigned)cur * 8192u
                    + (unsigned)((rf * 16 + c) * 128)
                    + (unsigned)((((4 * ks + g) ^ (c & 7)) * 16)));

        #pragma unroll
        for (int nf = 0; nf < 3; ++nf) {
            #pragma unroll
            for (int ks = 0; ks < 2; ++ks) {
                f16x8 bf = *(const f16x8*)(wt
                    + (size_t)(w * 48 + nf * 16 + c) * DM + t * 64 + ks * 32 + g * 8);
                #pragma unroll
                for (int rf = 0; rf < 4; ++rf)
                    acc[rf][nf] = __builtin_amdgcn_mfma_f32_16x16x32_f16(
                        af[rf][ks], bf, acc[rf][nf], 0, 0, 0);
            }
        }
        __syncthreads();
    }

    f16* const tile = (f16*)smem;
    #pragma unroll
    for (int rf = 0; rf < 4; ++rf)
        #pragma unroll
        for (int nf = 0; nf < 3; ++nf) {
            const int n  = w * 48 + nf * 16 + c;
            const float bb = biasf[n];
            #pragma unroll
            for (int r = 0; r < 4; ++r) {
                const int row = rf * 16 + 4 * g + r;
                tile[row * 392 + n] = (f16)(acc[rf][nf][r] + bb);
            }
        }
    __syncthreads();

    #pragma unroll
    for (int it = 0; it < 2; ++it) {
        const int u   = tid + it * 512;
        const int row = u >> 4;
        const int c8  = (u & 15) * 8;
        *(f16x8*)(qo + (size_t)(r0 + row) * DQK + c8) = *(const f16x8*)&tile[row * 392 + c8];
        *(f16x8*)(ko + (size_t)(r0 + row) * DQK + c8) = *(const f16x8*)&tile[row * 392 + 128 + c8];
    }
    const int gb = r0 >> 12;
    const int s0 = r0 & (SEQ - 1);
    #pragma unroll
    for (int it = 0; it < 2; ++it) {
        const int u  = tid + it * 512;
        const int d  = u >> 3;
        const int s8 = (u & 7) * 8;
        f16x8 vv;
        #pragma unroll
        for (int i = 0; i < 8; ++i) vv[i] = tile[(s8 + i) * 392 + 256 + d];
        *(f16x8*)(vto + ((size_t)gb * DQK + d) * SEQ + s0 + s8) = vv;
    }
}

// ---------------- Flash attention: r4 dataflow, 16 waves/block (4 per SIMD) ----------------
// grid 256 x 1024 thr. Block: 64 q-rows. Wave (wq 0..3, wk 0..3) = 16 q-rows x 32-kv slice
// of each 128-kv tile. K,V LDS-staged double-buffered (1 barrier/iter). P stays in
// registers: cvt_pkrtz + 8x ds_bpermute to PV A-frag layout. l via VALU; m,l per q=c lane.
__device__ __forceinline__ void stage16(const void* g, unsigned char* l) {
    __builtin_amdgcn_global_load_lds(
        (const __attribute__((address_space(1))) unsigned int*)g,
        (__attribute__((address_space(3))) unsigned int*)l, 16, 0, 0);
}

#define KOFF 0u        // 2 x 32 KB K double buffer
#define VOFF 65536u    // 2 x 32 KB V double buffer
#define MOFF 131072u
#define LOFF 132096u

__global__ __launch_bounds__(1024, 4) void attn_kernel(
    const f16* __restrict__ qg, const f16* __restrict__ kg,
    const f16* __restrict__ vtg, float* __restrict__ out)
{
    __shared__ __align__(16) unsigned char smem[133120];

    const int tid  = threadIdx.x;
    const int lane = tid & 63;
    const int w    = tid >> 6;      // 0..15
    const int wq   = w >> 2;        // 0..3
    const int wk   = w & 3;         // 0..3
    const int c    = lane & 15;
    const int g    = lane >> 4;     // 0..3

    const int bid = blockIdx.x;
    const int xcd = bid & 7;
    const int bb  = xcd >> 1;       // batch pinned to XCD pair (K/V L2-resident)
    const int qt  = (bid >> 3) | ((xcd & 1) << 5);
    const int q0  = qt * 64;

    const f16*  qb = qg  + (size_t)bb * SEQ * DQK;
    const char* kB = (const char*)(kg  + (size_t)bb * SEQ * DQK);
    const char* vB = (const char*)(vtg + (size_t)bb * DQK * SEQ);

    // Q frags (B-operand for swapped QK^T): q = q0 + wq*16 + c, d = ks*32 + 8g + i
    f16x8 qf[4];
    {
        const f16* qr = qb + (size_t)(q0 + wq * 16) * DQK;
        #pragma unroll
        for (int ks = 0; ks < 4; ++ks)
            qf[ks] = *(const f16x8*)(qr + c * DQK + ks * 32 + 8 * g);
    }

    f32x4 o[8];     // O[q = 4g+r][d = df*16 + c]
    #pragma unroll
    for (int f = 0; f < 8; ++f) o[f] = (f32x4)0.f;
    float m_run = -3e38f;   // per q = c (uniform across g after reduce)
    float l_run = 0.f;

    const unsigned wbase = (unsigned)w * 1024;

    auto stage_tiles = [&](int t, int pbuf) {
        const int kv0 = t * 128;
        unsigned char* kdst = smem + KOFF + (unsigned)pbuf * 32768u + wbase;
        unsigned char* vdst = smem + VOFF + (unsigned)pbuf * 32768u + wbase;
        #pragma unroll
        for (int cc = 0; cc < 2; ++cc) {
            const int j   = tid + cc * 1024;
            const int row = j >> 4;
            const int col = j & 15;
            const int sw  = (col ^ (row & 7)) * 16;
            stage16(kB + (size_t)(kv0 + row) * 256 + sw, kdst + cc * 16384);
            stage16(vB + (size_t)row * 8192 + (size_t)kv0 * 2 + sw, vdst + cc * 16384);
        }
    };

    // bpermute source-lane byte-addresses (loop-invariant)
    const int addr_h0 = (16 * (2 * (g & 1) + 0) + c) * 4;
    const int addr_h1 = (16 * (2 * (g & 1) + 1) + c) * 4;
    const bool hi_m = (g >= 2);

    stage_tiles(0, 0);
    __syncthreads();   // tile 0 ready

    for (int t = 0; t < 32; ++t) {
        const int pb = t & 1;
        unsigned char* const kbase = smem + KOFF + (unsigned)pb * 32768u;
        unsigned char* const vbase = smem + VOFF + (unsigned)pb * 32768u;

        if (t < 31) stage_tiles(t + 1, pb ^ 1);   // drains at end-of-iter barrier

        // ---- swapped QK^T: S^T[kv 32][q 16], A = K frag (LDS), B = Q frag (reg) ----
        f32x4 s[2];   // [m (kv16)]; C: col q = c, row kv = m*16 + 4g + r
        s[0] = (f32x4)0.f; s[1] = (f32x4)0.f;
        __builtin_amdgcn_s_setprio(1);
        #pragma unroll
        for (int ks = 0; ks < 4; ++ks) {
            #pragma unroll
            for (int m = 0; m < 2; ++m) {
                f16x8 kf = *(const f16x8*)(kbase
                    + (unsigned)(wk * 32 + m * 16 + c) * 256u
                    + (unsigned)(((4 * ks + g) ^ (c & 7)) * 16));
                s[m] = __builtin_amdgcn_mfma_f32_16x16x32_f16(kf, qf[ks], s[m], 0, 0, 0);
            }
        }
        __builtin_amdgcn_s_setprio(0);

        // ---- softmax max (per q = c) ----
        float mt;
        {
            float a0 = fmaxf(fmaxf(s[0][0], s[0][1]), fmaxf(s[0][2], s[0][3]));
            float a1 = fmaxf(fmaxf(s[1][0], s[1][1]), fmaxf(s[1][2], s[1][3]));
            float v  = fmaxf(a0, a1);
            v = fmaxf(v, __shfl_xor(v, 16, 64));
            v = fmaxf(v, __shfl_xor(v, 32, 64));
            mt = v;
        }

        bool need = (mt > m_run + DEFER_THR);
        if (__any(need)) {
            float mn = fmaxf(m_run, mt);
            float al = __builtin_amdgcn_exp2f(m_run - mn);
            m_run = mn;
            l_run *= al;
            float alo[4];
            #pragma unroll
            for (int r = 0; r < 4; ++r) alo[r] = __shfl(al, 4 * g + r, 16);
            #pragma unroll
            for (int f = 0; f < 8; ++f)
                #pragma unroll
                for (int r = 0; r < 4; ++r) o[f][r] *= alo[r];
        }

        // e = exp2(S^T - m) in place; l accumulation via VALU + 2 shuffles
        #pragma unroll
        for (int m = 0; m < 2; ++m)
            #pragma unroll
            for (int r = 0; r < 4; ++r)
                s[m][r] = __builtin_amdgcn_exp2f(s[m][r] - m_run);

        {
            float ls = ((s[0][0] + s[0][1]) + (s[0][2] + s[0][3]))
                     + ((s[1][0] + s[1][1]) + (s[1][2] + s[1][3]));
            ls += __shfl_xor(ls, 16, 64);
            ls += __shfl_xor(ls, 32, 64);
            l_run += ls;
        }

        // pack to f16 pairs; exchange to PV A-frag layout via bpermute
        int u[2][2];
        #pragma unroll
        for (int m = 0; m < 2; ++m)
            #pragma unroll
            for (int p = 0; p < 2; ++p) {
                auto h2 = __builtin_amdgcn_cvt_pkrtz(s[m][2 * p], s[m][2 * p + 1]);
                u[m][p] = __builtin_bit_cast(int, h2);
            }

        f16x8 pa;
        {
            int paw[4];
            #pragma unroll
            for (int j = 0; j < 4; ++j) {
                const int addr = (j >> 1) ? addr_h1 : addr_h0;
                int tA = __builtin_amdgcn_ds_bpermute(addr, u[0][j & 1]);
                int tB = __builtin_amdgcn_ds_bpermute(addr, u[1][j & 1]);
                paw[j] = hi_m ? tB : tA;
            }
            int4 pw = make_int4(paw[0], paw[1], paw[2], paw[3]);
            pa = __builtin_bit_cast(f16x8, pw);
        }

        // ---- PV: O[16 q][128 d] += P[16 q][32 kv] * V[32 kv][128 d] ----
        __builtin_amdgcn_s_setprio(1);
        #pragma unroll
        for (int df = 0; df < 8; ++df) {
            f16x8 vf = *(const f16x8*)(vbase
                + (unsigned)(df * 16 + c) * 256u
                + (unsigned)(((4 * wk + g) ^ (c & 7)) * 16));
            o[df] = __builtin_amdgcn_mfma_f32_16x16x32_f16(pa, vf, o[df], 0, 0, 0);
        }
        __builtin_amdgcn_s_setprio(0);

        __syncthreads();   // this tile's reads done; next tile's staging drained
    }

    // ship m, l to O row domain (q-local = 4g + r)
    float m_o[4], l_o[4];
    #pragma unroll
    for (int r = 0; r < 4; ++r) {
        m_o[r] = __shfl(m_run, 4 * g + r, 16);
        l_o[r] = __shfl(l_run, 4 * g + r, 16);
    }

    float* const mld  = (float*)(smem + MOFF);   // [16 waves][16 rows]
    float* const lld  = (float*)(smem + LOFF);
    float* const olds = (float*)smem;            // 64 rows x 132 f32, reuses K region

    if (c == 0) {
        #pragma unroll
        for (int r = 0; r < 4; ++r) {
            mld[w * 16 + 4 * g + r] = m_o[r];
            lld[w * 16 + 4 * g + r] = l_o[r];
        }
    }
    __syncthreads();

    float ms_s[4], lt_s[4];
    if (wk == 0) {
        #pragma unroll
        for (int r = 0; r < 4; ++r) {
            const int rl = 4 * g + r;
            float mm = m_o[r];
            #pragma unroll
            for (int i = 1; i < 4; ++i) mm = fmaxf(mm, mld[(wq * 4 + i) * 16 + rl]);
            ms_s[r] = mm;
            float a0 = __builtin_amdgcn_exp2f(m_o[r] - mm);
            float lt = a0 * l_o[r];
            #pragma unroll
            for (int i = 1; i < 4; ++i)
                lt += __builtin_amdgcn_exp2f(mld[(wq * 4 + i) * 16 + rl] - mm)
                      * lld[(wq * 4 + i) * 16 + rl];
            lt_s[r] = lt;
            #pragma unroll
            for (int f = 0; f < 8; ++f) o[f][r] *= a0;
        }
    }

    // 3-phase accumulation through the 34 KB buffer
    for (int ph = 1; ph < 4; ++ph) {
        if (wk == ph) {
            #pragma unroll
            for (int f = 0; f < 8; ++f)
                #pragma unroll
                for (int r = 0; r < 4; ++r)
                    olds[(size_t)(wq * 16 + 4 * g + r) * 132 + f * 16 + c] = o[f][r];
        }
        __syncthreads();
        if (wk == 0) {
            #pragma unroll
            for (int r = 0; r < 4; ++r) {
                const int rl = 4 * g + r;
                const float ai = __builtin_amdgcn_exp2f(mld[(wq * 4 + ph) * 16 + rl] - ms_s[r]);
                #pragma unroll
                for (int f = 0; f < 8; ++f)
                    o[f][r] += ai * olds[(size_t)(wq * 16 + rl) * 132 + f * 16 + c];
            }
        }
        __syncthreads();
    }

    if (wk == 0) {
        #pragma unroll
        for (int r = 0; r < 4; ++r) {
            const int rl = 4 * g + r;
            const int q  = q0 + wq * 16 + rl;
            const float inv = 1.0f / lt_s[r];
            float* orow = out + ((size_t)bb * SEQ + q) * DQK;
            #pragma unroll
            for (int f = 0; f < 8; ++f)
                orow[f * 16 + c] = o[f][r] * inv;
        }
    }
}

extern "C" void kernel_launch(void* const* d_in, const int* in_sizes, int n_in,
                              void* d_out, int out_size, void* d_ws, size_t ws_size,
                              hipStream_t stream) {
    const float* x  = (const float*)d_in[0];
    const float* Wq = (const float*)d_in[1];
    const float* bq = (const float*)d_in[2];
    const float* Wk = (const float*)d_in[3];
    const float* bk = (const float*)d_in[4];
    const float* Wv = (const float*)d_in[5];
    const float* bv = (const float*)d_in[6];
    float* outp = (float*)d_out;

    f16*   qf    = (f16*)d_ws;
    f16*   kf    = qf + (size_t)BATCH * SEQ * DQK;
    f16*   vt    = kf + (size_t)BATCH * SEQ * DQK;
    f16*   wt    = vt + (size_t)BATCH * DQK * SEQ;
    float* biasf = (float*)(wt + (size_t)384 * DM);

    wcvt_kernel<<<24, 256, 0, stream>>>(Wq, bq, Wk, bk, Wv, bv, wt, biasf);

    proj_kernel<<<BATCH * SEQ / 64, 512, 0, stream>>>(x, wt, biasf, qf, kf, vt);

    attn_kernel<<<256, 1024, 0, stream>>>(qf, kf, vt, outp);
}